// Round 5
// baseline (251.893 us; speedup 1.0000x reference)
//
#include <hip/hip_runtime.h>
#include <hip/hip_bf16.h>
#include <cstdint>
#include <cstddef>

// ---------- types ----------
typedef _Float16 f16x8 __attribute__((ext_vector_type(8)));
typedef float    f32x4 __attribute__((ext_vector_type(4)));

#define VOC    50000
#define W2     4224      // unified K: 4096 (kron) + 128 (concat)
#define NSTAGE 33        // 33 stages x 128 k = 4224
#define STG    8192      // elems per 128-k stage (128 k x 64 n) = 16 KB
#define XSTR   72        // LDS row stride in f16 elems (144 B, 16B-aligned)
#define TPW    4         // trees per WG in k_tree (256 thr, 2 WGs/CU)
#define IPW    16        // items per WG in k_final

// ---------- static device scratch ----------
__device__ __attribute__((aligned(256))) unsigned short g_vocT[(size_t)VOC * 64];   // f16
__device__ __attribute__((aligned(256))) unsigned short g_roots[2048 * 64];         // f16
// weights (f16) in stage-fragment order:
//   d = s*8192 + kbl*2048 + nt*512 + q*128 + sub*8 + z
//   maps to W[n][k]: n = nt*16 + sub, k = s*128 + kbl*32 + q*8 + z
// -> a wave's b128 read for (kbl, nt) is a contiguous 1KB block (conflict-free)
__device__ __attribute__((aligned(256))) unsigned short g_cpstU[(size_t)NSTAGE * STG];
__device__ __attribute__((aligned(256))) unsigned short g_cprtU[(size_t)NSTAGE * STG];
__device__ float g_smw[7 * 64];
__device__ float g_smb[7];
__device__ float g_biasC[64];   // cps_b + cpst_b
__device__ float g_biasF[64];   // cpr_b + cprt_b

__device__ __forceinline__ float b2f(unsigned short u) {
    unsigned int x = ((unsigned int)u) << 16;
    return __builtin_bit_cast(float, x);
}
__device__ __forceinline__ unsigned short f2b(float f) {
    return __builtin_bit_cast(unsigned short, (__bf16)f);
}
__device__ __forceinline__ unsigned short f2h(float f) {
    return __builtin_bit_cast(unsigned short, (_Float16)f);
}
__device__ __forceinline__ float scrub(float v) {
    return fminf(fmaxf(v, -64.f), 64.f);
}
__device__ __forceinline__ float ldf(const void* p, size_t i, int isb) {
    return isb ? b2f(((const unsigned short*)p)[i]) : ((const float*)p)[i];
}
__device__ __forceinline__ int detect_isb(const void* voc_b) {
    const unsigned int* p = (const unsigned int*)voc_b;
    int ok = 1;
    for (int k = 0; k < 32; k++) {
        float v = b2f((unsigned short)(p[k] & 0xFFFFu));
        if (!(fabsf(v) <= 0.0502f)) ok = 0;
    }
    return ok;
}
// async global->LDS, 16B per lane; LDS dest must be wave-uniform base + lane*16
__device__ __forceinline__ void gload16(const unsigned short* g, unsigned short* l) {
    __builtin_amdgcn_global_load_lds(
        (const __attribute__((address_space(1))) void*)g,
        (__attribute__((address_space(3))) void*)l, 16, 0, 0);
}

// ---------- kernel: fused preprocessing ----------
// blocks [0,512): canonicalize weights into stage-fragment order (f16)
// blocks [512,512+782): voc_w (64 x 50000) -> g_vocT[50000][64] f16, fold voc_b
__global__ __launch_bounds__(256) void k_prep(
    const void* voc_w, const void* voc_b,
    const void* cps_w, const void* cps_b, const void* cpst_w, const void* cpst_b,
    const void* cpr_w, const void* cpr_b, const void* cprt_w, const void* cprt_b,
    const void* sm_w, const void* sm_b)
{
    __shared__ float tile[64][65];
    __shared__ float vb[64];
    const int isb = detect_isb(voc_b);
    if (blockIdx.x < 512) {
        int gid = blockIdx.x * 256 + threadIdx.x;
        int stride = 512 * 256;
        for (int d = gid; d < 64 * W2; d += stride) {
            int s    = d / STG;
            int rem  = d - s * STG;
            int kbl  = rem >> 11;
            int rem2 = rem & 2047;
            int nt   = rem2 >> 9;
            int rem3 = rem2 & 511;
            int q    = rem3 >> 7;
            int rem4 = rem3 & 127;
            int sub  = rem4 >> 3;
            int z    = rem4 & 7;
            int n    = nt * 16 + sub;
            int k    = s * 128 + kbl * 32 + q * 8 + z;
            float v1 = (k < 4096) ? ldf(cpst_w, (size_t)n * 4096 + k, isb)
                                  : ldf(cps_w,  (size_t)n * 128 + (k - 4096), isb);
            g_cpstU[d] = f2h(v1);
            float v2 = (k < 4096) ? ldf(cprt_w, (size_t)n * 4096 + k, isb)
                                  : ldf(cpr_w,  (size_t)n * 128 + (k - 4096), isb);
            g_cprtU[d] = f2h(v2);
        }
        for (int i = gid; i < 448; i += stride) g_smw[i] = ldf(sm_w, i, isb);
        if (gid < 64) {
            g_biasC[gid] = ldf(cps_b, gid, isb) + ldf(cpst_b, gid, isb);
            g_biasF[gid] = ldf(cpr_b, gid, isb) + ldf(cprt_b, gid, isb);
        }
        if (gid < 7) g_smb[gid] = ldf(sm_b, gid, isb);
    } else {
        int t = threadIdx.x;
        if (t < 64) vb[t] = ldf(voc_b, t, isb);
        int v0 = (blockIdx.x - 512) * 64;
        int vl = t & 63, dr = t >> 6;
        #pragma unroll
        for (int i = 0; i < 16; i++) {
            int d = dr * 16 + i;
            int v = v0 + vl;
            tile[vl][d] = (v < VOC) ? ldf(voc_w, (size_t)d * VOC + v, isb) : 0.f;
        }
        __syncthreads();
        int dl = t & 63, vr0 = t >> 6;
        #pragma unroll
        for (int i = 0; i < 16; i++) {
            int vr = vr0 * 16 + i;
            int v = v0 + vr;
            if (v < VOC) g_vocT[(size_t)v * 64 + dl] = f2h(tile[vr][dl] + vb[dl]);
        }
    }
}

// epilogue for owned chunk CO (literal index!): add bias, tanh, store (f16)
#define EPILOGUE(CO)                                                          \
    if (lv < 5) {                                                             \
        _Pragma("unroll")                                                     \
        for (int nt = 0; nt < 4; nt++) {                                      \
            int e = nt * 16 + sub;                                            \
            _Pragma("unroll")                                                 \
            for (int rr = 0; rr < 4; rr++) {                                  \
                int m = chv[CO] * 16 + q * 4 + rr;                            \
                if (m < nodes) {                                              \
                    int t2 = m >> lg, n2 = m & (cnew - 1);                    \
                    Xs[(t2 * 64 + n2) * XSTR + e] =                           \
                        f2h(tanhf(scrub(acc[CO][nt][rr] + biasC[e])));        \
                }                                                             \
            }                                                                 \
        }                                                                     \
    } else {                                                                  \
        _Pragma("unroll")                                                     \
        for (int nt = 0; nt < 4; nt++) {                                      \
            int e = nt * 16 + sub;                                            \
            _Pragma("unroll")                                                 \
            for (int rr = 0; rr < 4; rr++) {                                  \
                int m = q * 4 + rr;                                           \
                if (m < TPW)                                                  \
                    g_roots[((size_t)wg * TPW + m) * 64 + e] =                \
                        f2h(tanhf(scrub(acc[CO][nt][rr] + biasC[e])));        \
            }                                                                 \
        }                                                                     \
    }

// send partial acc for chunk CS (literal) to this wave's scratch slot (in Bs)
#define EXSEND(CS)                                                            \
    { _Pragma("unroll")                                                       \
      for (int nt = 0; nt < 4; nt++)                                          \
          *(f32x4*)(exch + wave * 1024 + nt * 256 + lane * 4) = acc[CS][nt]; }

// receive partner's partial for owned chunk CO (literal) and accumulate
#define EXRECV(CO)                                                            \
    { _Pragma("unroll")                                                       \
      for (int nt = 0; nt < 4; nt++) {                                        \
          f32x4 v_ = *(const f32x4*)(exch + (wave ^ 1) * 1024 + nt * 256 + lane * 4); \
          _Pragma("unroll")                                                   \
          for (int z = 0; z < 4; z++) acc[CO][nt][z] += v_[z];                \
      } }

// ---------- kernel: full tree composition ----------
// 256 threads = 4 waves = 2 pairs; 512 WGs = 2 WGs/CU (the overlap lever:
// two barrier-independent WGs keep LDS/VALU/MFMA pipes co-busy).
// Pair p = wave>>1 owns M-chunks ch = p + 2c; within a pair, wave half = wave&1
// computes k-blocks kbl = 2*half+{0,1} of each 128-K stage (i = 2s+half).
// Weights stream via global_load_lds into double-buffered Bs, ONE barrier per
// stage.  K-partial exchange reuses Bs as scratch (no DMA in flight then);
// next level's stage-0 DMA is issued after the exchange (+1 barrier/level).
__global__ __launch_bounds__(256, 2) void k_tree(const int* __restrict__ lleaf,
                                                 const int* __restrict__ rleaf)
{
    __shared__ __attribute__((aligned(16))) unsigned short Xs[256 * XSTR];  // 36864 B
    __shared__ __attribute__((aligned(16))) unsigned short Bs[2][STG];      // 32768 B
    __shared__ float biasC[64];
    const int tid = threadIdx.x;
    const int wg  = blockIdx.x;

    // ---- issue weight stage 0 into Bs[0] (overlaps leaf gather) ----
    #pragma unroll
    for (int j = 0; j < 4; j++)
        gload16(g_cpstU + j * 2048 + tid * 8, Bs[0] + j * 2048 + tid * 8);

    if (tid < 64) biasC[tid] = g_biasC[tid];

    // ---- leaf gather: row tid = (tree tid>>6, leaf tid&63) ----
    {
        int t = tid >> 6, i = tid & 63;
        int gidx = wg * TPW + t;                 // 0..1023 left, 1024..2047 right
        int b = (gidx < 1024) ? gidx : gidx - 1024;
        const int* lv2 = (gidx < 1024) ? lleaf : rleaf;
        int idx = lv2[b * 64 + i];
        idx = (idx < 0) ? 0 : ((idx >= VOC) ? VOC - 1 : idx);
        const uint4* src = (const uint4*)(g_vocT + (size_t)idx * 64);
        uint4* dst = (uint4*)(Xs + tid * XSTR);
        #pragma unroll
        for (int z = 0; z < 8; z++) dst[z] = src[z];
    }

    __syncthreads();   // Xs + biasC ready; stage-0 DMA drained (own vmcnt)

    const int lane = tid & 63, wave = tid >> 6;
    const int q = lane >> 4, sub = lane & 15;
    const int p = wave >> 1, half = wave & 1;
    float* exch = (float*)&Bs[0][0];             // 16 KB scratch, level boundary only
    int par = 0;

    for (int lv = 0; lv < 6; lv++) {
        const int lg = 5 - lv;
        const int cnew = 1 << lg;
        const int nodes = TPW << lg;             // 128,64,32,16,8,4
        const int nchunks = (nodes + 15) >> 4;   // 8,4,2,1,1,1

        // ---- hoist: chunk geometry + L fragments as raw f16 (registers) ----
        int act[4], chv[4], slotL[4];
        f16x8 La[4][2];
        #pragma unroll
        for (int c = 0; c < 4; c++) {
            int ch = p + 2 * c;
            act[c] = (ch < nchunks);
            chv[c] = ch;
            int m = ch * 16 + sub;
            if (!act[c] || m >= nodes) m = 0;
            int t = m >> lg, n = m & (cnew - 1);
            slotL[c] = (t * 64 + 2 * n) * XSTR;
            La[c][0] = *(const f16x8*)(Xs + slotL[c] + q * 8);
            La[c][1] = *(const f16x8*)(Xs + slotL[c] + 32 + q * 8);
        }

        f32x4 acc[4][4];                         // [chunk][ntile] K-partials
        #pragma unroll
        for (int c = 0; c < 4; c++)
            #pragma unroll
            for (int nt = 0; nt < 4; nt++)
                #pragma unroll
                for (int z = 0; z < 4; z++) acc[c][nt][z] = 0.f;

        for (int s = 0; s < NSTAGE; s++) {
            // issue next stage into the other buffer (stage 0 of the next
            // level is issued after the exchange instead)
            if (s < NSTAGE - 1) {
                const unsigned short* src = g_cpstU + (size_t)(s + 1) * STG;
                unsigned short* dst = Bs[par ^ 1];
                #pragma unroll
                for (int j = 0; j < 4; j++)
                    gload16(src + j * 2048 + tid * 8, dst + j * 2048 + tid * 8);
            }
            const unsigned short* Bp = Bs[par];
            if (act[0]) {                        // act monotone in c: act[0] == any
                if (s < 32) {                    // kron: this wave does i = 2s+half
                    const int i = 2 * s + half;
                    _Float16 liv[4];
                    #pragma unroll
                    for (int c = 0; c < 4; c++)
                        liv[c] = __builtin_bit_cast(_Float16, Xs[slotL[c] + i]);
                    #pragma unroll
                    for (int p2 = 0; p2 < 2; p2++) {
                        const unsigned short* bb = Bp + (2 * half + p2) * 2048 + lane * 8;
                        f16x8 b0 = *(const f16x8*)(bb);
                        f16x8 b1 = *(const f16x8*)(bb + 512);
                        f16x8 b2 = *(const f16x8*)(bb + 1024);
                        f16x8 b3 = *(const f16x8*)(bb + 1536);
                        #pragma unroll
                        for (int c = 0; c < 4; c++) {
                            if (!act[c]) continue;
                            f16x8 afr = La[c][p2] * liv[c];   // v_pk_mul_f16 x4
                            acc[c][0] = __builtin_amdgcn_mfma_f32_16x16x32_f16(afr, b0, acc[c][0], 0, 0, 0);
                            acc[c][1] = __builtin_amdgcn_mfma_f32_16x16x32_f16(afr, b1, acc[c][1], 0, 0, 0);
                            acc[c][2] = __builtin_amdgcn_mfma_f32_16x16x32_f16(afr, b2, acc[c][2], 0, 0, 0);
                            acc[c][3] = __builtin_amdgcn_mfma_f32_16x16x32_f16(afr, b3, acc[c][3], 0, 0, 0);
                        }
                    }
                } else {                         // concat: half=0 -> L, half=1 -> R
                    #pragma unroll
                    for (int p2 = 0; p2 < 2; p2++) {
                        const unsigned short* bb = Bp + (2 * half + p2) * 2048 + lane * 8;
                        f16x8 b0 = *(const f16x8*)(bb);
                        f16x8 b1 = *(const f16x8*)(bb + 512);
                        f16x8 b2 = *(const f16x8*)(bb + 1024);
                        f16x8 b3 = *(const f16x8*)(bb + 1536);
                        #pragma unroll
                        for (int c = 0; c < 4; c++) {
                            if (!act[c]) continue;
                            f16x8 A = *(const f16x8*)(Xs + slotL[c] + half * XSTR + p2 * 32 + q * 8);
                            acc[c][0] = __builtin_amdgcn_mfma_f32_16x16x32_f16(A, b0, acc[c][0], 0, 0, 0);
                            acc[c][1] = __builtin_amdgcn_mfma_f32_16x16x32_f16(A, b1, acc[c][1], 0, 0, 0);
                            acc[c][2] = __builtin_amdgcn_mfma_f32_16x16x32_f16(A, b2, acc[c][2], 0, 0, 0);
                            acc[c][3] = __builtin_amdgcn_mfma_f32_16x16x32_f16(A, b3, acc[c][3], 0, 0, 0);
                        }
                    }
                }
            }
            __syncthreads();   // own DMA drained; all reads of Bs[par] done
            par ^= 1;
        }

        // ---- pair exchange + epilogue (Bs reused as scratch; no DMA in
        // flight: next level's stage-0 is issued after) ----
        // round 0: chunks {0,1}; owned(c) iff (c&1)==half
        if (half == 0) { if (act[1]) EXSEND(1) } else { if (act[0]) EXSEND(0) }
        __syncthreads();
        if (half == 0) {
            if (act[0]) { EXRECV(0) EPILOGUE(0) }
        } else {
            if (act[1]) { EXRECV(1) EPILOGUE(1) }
        }
        __syncthreads();
        // round 1: chunks {2,3}
        if (half == 0) { if (act[3]) EXSEND(3) } else { if (act[2]) EXSEND(2) }
        __syncthreads();
        if (half == 0) {
            if (act[2]) { EXRECV(2) EPILOGUE(2) }
        } else {
            if (act[3]) { EXRECV(3) EPILOGUE(3) }
        }
        __syncthreads();   // Xs stable; scratch reads done

        if (lv < 5) {
            // issue stage-0 DMA for the next level into Bs[0]
            #pragma unroll
            for (int j = 0; j < 4; j++)
                gload16(g_cpstU + j * 2048 + tid * 8, Bs[0] + j * 2048 + tid * 8);
            __syncthreads();   // drained: Bs[0] ready
            par = 0;
        }
    }
}

// ---------- kernel: final cpr/cprt + leaky_relu + softmax ----------
// 64 WGs x 16 items, 4 waves; wave w owns N-tile nt = w (cols w*16..w*16+15).
// Same gload_lds single-barrier staging; f16 pipeline.
__global__ __launch_bounds__(256, 2) void k_final(const void* __restrict__ voc_b,
                                                  void* __restrict__ out)
{
    __shared__ __attribute__((aligned(16))) unsigned short Lv[IPW * XSTR], Rv[IPW * XSTR];
    __shared__ __attribute__((aligned(16))) unsigned short Bs[2][STG];
    __shared__ float actS[IPW][65];
    __shared__ float smw[7][64];
    __shared__ float smbS[7];
    __shared__ float biasF[64];
    const int tid = threadIdx.x, wg = blockIdx.x;
    const int isb = detect_isb(voc_b);

    // issue weight stage 0 into Bs[0]
    #pragma unroll
    for (int j = 0; j < 4; j++)
        gload16(g_cprtU + j * 2048 + tid * 8, Bs[0] + j * 2048 + tid * 8);

    if (tid < 64) biasF[tid] = g_biasF[tid];
    if (tid < 7)  smbS[tid] = g_smb[tid];
    for (int z = tid; z < 448; z += 256) smw[z >> 6][z & 63] = g_smw[z];

    {   // stage l and r roots for this WG's 16 items: 256 threads x 1 uint4
        int side = tid >> 7, idx = tid & 127;
        int item = idx >> 3, piece = idx & 7;
        const uint4* s4 = (const uint4*)(g_roots +
            ((size_t)(side * 1024) + (size_t)wg * IPW + item) * 64 + piece * 8);
        uint4* d4 = (uint4*)((side ? Rv : Lv) + item * XSTR + piece * 8);
        *d4 = *s4;
    }

    __syncthreads();   // roots + smem ready; stage-0 DMA drained

    const int lane = tid & 63, w = tid >> 6;
    const int q = lane >> 4, sub = lane & 15;
    const int rowLo = sub * XSTR;                // item = sub (A-operand rows)

    f16x8 Ra[2];                                 // kron = l[i] * r[j]
    Ra[0] = *(const f16x8*)(Rv + rowLo + q * 8);
    Ra[1] = *(const f16x8*)(Rv + rowLo + 32 + q * 8);

    f32x4 acc;
    #pragma unroll
    for (int z = 0; z < 4; z++) acc[z] = 0.f;

    int par = 0;
    for (int s = 0; s < NSTAGE; s++) {
        if (s < NSTAGE - 1) {
            const unsigned short* src = g_cprtU + (size_t)(s + 1) * STG;
            unsigned short* dst = Bs[par ^ 1];
            #pragma unroll
            for (int j = 0; j < 4; j++)
                gload16(src + j * 2048 + tid * 8, dst + j * 2048 + tid * 8);
        }
        const unsigned short* Bp = Bs[par];
        if (s < 32) {
            #pragma unroll
            for (int ii = 0; ii < 2; ii++) {
                int i = 2 * s + ii;
                _Float16 li = __builtin_bit_cast(_Float16, Lv[rowLo + i]);
                #pragma unroll
                for (int p2 = 0; p2 < 2; p2++) {
                    int kbl = 2 * ii + p2;
                    f16x8 bfr = *(const f16x8*)(Bp + kbl * 2048 + w * 512 + lane * 8);
                    f16x8 afr = Ra[p2] * li;
                    acc = __builtin_amdgcn_mfma_f32_16x16x32_f16(afr, bfr, acc, 0, 0, 0);
                }
            }
        } else {                                 // concat(l, r)
            f16x8 A4[4];
            A4[0] = *(const f16x8*)(Lv + rowLo + q * 8);
            A4[1] = *(const f16x8*)(Lv + rowLo + 32 + q * 8);
            A4[2] = *(const f16x8*)(Rv + rowLo + q * 8);
            A4[3] = *(const f16x8*)(Rv + rowLo + 32 + q * 8);
            #pragma unroll
            for (int kbl = 0; kbl < 4; kbl++) {
                f16x8 bfr = *(const f16x8*)(Bp + kbl * 2048 + w * 512 + lane * 8);
                acc = __builtin_amdgcn_mfma_f32_16x16x32_f16(A4[kbl], bfr, acc, 0, 0, 0);
            }
        }
        __syncthreads();
        par ^= 1;
    }

    // epilogue: bias + leaky_relu -> LDS  (actS disjoint from stage-loop LDS)
    {
        int e = w * 16 + sub;
        #pragma unroll
        for (int rr = 0; rr < 4; rr++) {
            int item = q * 4 + rr;
            float v = scrub(acc[rr] + biasF[e]);
            v = (v > 0.f) ? v : 0.01f * v;
            actS[item][e] = v;
        }
    }
    __syncthreads();

    if (tid < IPW) {
        float lg[7];
        #pragma unroll
        for (int j = 0; j < 7; j++) lg[j] = smbS[j];
        for (int e = 0; e < 64; e++) {
            float a = actS[tid][e];
            #pragma unroll
            for (int j = 0; j < 7; j++) lg[j] += smw[j][e] * a;
        }
        float mx = lg[0];
        #pragma unroll
        for (int j = 1; j < 7; j++) mx = fmaxf(mx, lg[j]);
        float s = 0.f, pr[7];
        #pragma unroll
        for (int j = 0; j < 7; j++) { pr[j] = expf(lg[j] - mx); s += pr[j]; }
        float inv = 1.f / s;
        size_t b = (size_t)wg * IPW + tid;
        if (isb) {
            unsigned short* o = (unsigned short*)out;
            #pragma unroll
            for (int j = 0; j < 7; j++) o[b * 7 + j] = f2b(pr[j] * inv);
        } else {
            float* o = (float*)out;
            #pragma unroll
            for (int j = 0; j < 7; j++) o[b * 7 + j] = pr[j] * inv;
        }
    }
}

// ---------- host launcher ----------
extern "C" void kernel_launch(void* const* d_in, const int* in_sizes, int n_in,
                              void* d_out, int out_size, void* d_ws, size_t ws_size,
                              hipStream_t stream) {
    const int* lleaf = (const int*)d_in[0];
    const int* rleaf = (const int*)d_in[1];
    const void* voc_w  = d_in[2];
    const void* voc_b  = d_in[3];
    const void* cps_w  = d_in[4];
    const void* cps_b  = d_in[5];
    const void* cpst_w = d_in[6];
    const void* cpst_b = d_in[7];
    const void* cpr_w  = d_in[8];
    const void* cpr_b  = d_in[9];
    const void* cprt_w = d_in[10];
    const void* cprt_b = d_in[11];
    const void* sm_w   = d_in[12];
    const void* sm_b   = d_in[13];

    k_prep<<<512 + (VOC + 63) / 64, 256, 0, stream>>>(
        voc_w, voc_b, cps_w, cps_b, cpst_w, cpst_b,
        cpr_w, cpr_b, cprt_w, cprt_b, sm_w, sm_b);
    k_tree<<<2048 / TPW, 256, 0, stream>>>(lleaf, rleaf);
    k_final<<<64, 256, 0, stream>>>(voc_b, (unsigned short*)d_out);
}

// Round 6
// 225.990 us; speedup vs baseline: 1.1146x; 1.1146x over previous
//
#include <hip/hip_runtime.h>
#include <hip/hip_bf16.h>
#include <cstdint>
#include <cstddef>

// ---------- types ----------
typedef _Float16 f16x8 __attribute__((ext_vector_type(8)));
typedef float    f32x4 __attribute__((ext_vector_type(4)));

#define VOC    50000
// k_tree (symmetric-folded): K = 36 blocks * 64 + 128 concat = 2432 = 19 stages
#define W2T    2432
#define NSTG_T 19
// k_final (asymmetric kron): K = 4096 + 128 = 4224 = 33 stages
#define W2F    4224
#define NSTG_F 33
#define STG    8192      // elems per 128-k stage (128 k x 64 n) = 16 KB
#define XSTR   72        // LDS row stride in f16 elems (144 B, 16B-aligned)
#define TPW    8         // trees per WG in k_tree (512 thr, 1 WG/CU)
#define IPW    16        // items per WG in k_final

// ---------- static device scratch ----------
__device__ __attribute__((aligned(256))) unsigned short g_vocT[(size_t)VOC * 64];   // f16
__device__ __attribute__((aligned(256))) unsigned short g_roots[2048 * 64];         // f16
// weights (f16) in stage-fragment order:
//   d = s*8192 + kbl*2048 + nt*512 + q*128 + sub*8 + z
//   maps to W[n][k]: n = nt*16 + sub, k = s*128 + kbl*32 + q*8 + z
// g_cpstU: k < 2304 -> symmetric-folded kron block b=k>>6 (see k_prep);
//          k >= 2304 -> concat (cps_w).
__device__ __attribute__((aligned(256))) unsigned short g_cpstU[(size_t)NSTG_T * STG];
__device__ __attribute__((aligned(256))) unsigned short g_cprtU[(size_t)NSTG_F * STG];
__device__ float g_smw[7 * 64];
__device__ float g_smb[7];
__device__ float g_biasC[64];   // cps_b + cpst_b
__device__ float g_biasF[64];   // cpr_b + cprt_b

__device__ __forceinline__ float b2f(unsigned short u) {
    unsigned int x = ((unsigned int)u) << 16;
    return __builtin_bit_cast(float, x);
}
__device__ __forceinline__ unsigned short f2b(float f) {
    return __builtin_bit_cast(unsigned short, (__bf16)f);
}
__device__ __forceinline__ unsigned short f2h(float f) {
    return __builtin_bit_cast(unsigned short, (_Float16)f);
}
__device__ __forceinline__ float scrub(float v) {
    return fminf(fmaxf(v, -64.f), 64.f);
}
__device__ __forceinline__ float ldf(const void* p, size_t i, int isb) {
    return isb ? b2f(((const unsigned short*)p)[i]) : ((const float*)p)[i];
}
__device__ __forceinline__ int detect_isb(const void* voc_b) {
    const unsigned int* p = (const unsigned int*)voc_b;
    int ok = 1;
    for (int k = 0; k < 32; k++) {
        float v = b2f((unsigned short)(p[k] & 0xFFFFu));
        if (!(fabsf(v) <= 0.0502f)) ok = 0;
    }
    return ok;
}
// async global->LDS, 16B per lane; LDS dest must be wave-uniform base + lane*16
__device__ __forceinline__ void gload16(const unsigned short* g, unsigned short* l) {
    __builtin_amdgcn_global_load_lds(
        (const __attribute__((address_space(1))) void*)g,
        (__attribute__((address_space(3))) void*)l, 16, 0, 0);
}

// ---------- kernel: fused preprocessing ----------
// blocks [0,512): canonicalize weights (cpst: symmetric fold; cprt: plain)
// blocks [512,512+782): voc_w (64 x 50000) -> g_vocT[50000][64] f16, fold voc_b
__global__ __launch_bounds__(256) void k_prep(
    const void* voc_w, const void* voc_b,
    const void* cps_w, const void* cps_b, const void* cpst_w, const void* cpst_b,
    const void* cpr_w, const void* cpr_b, const void* cprt_w, const void* cprt_b,
    const void* sm_w, const void* sm_b)
{
    __shared__ float tile[64][65];
    __shared__ float vb[64];
    const int isb = detect_isb(voc_b);
    if (blockIdx.x < 512) {
        int gid = blockIdx.x * 256 + threadIdx.x;
        int stride = 512 * 256;
        // ---- g_cpstU: symmetric-folded kron + concat (19 stages) ----
        for (int d = gid; d < 64 * W2T; d += stride) {
            int s    = d / STG;
            int rem  = d - s * STG;
            int kbl  = rem >> 11;
            int rem2 = rem & 2047;
            int nt   = rem2 >> 9;
            int rem3 = rem2 & 511;
            int q    = rem3 >> 7;
            int rem4 = rem3 & 127;
            int sub  = rem4 >> 3;
            int z    = rem4 & 7;
            int n    = nt * 16 + sub;
            int k    = s * 128 + kbl * 32 + q * 8 + z;
            float w;
            if (k < 2304) {
                int b = k >> 6, slot = k & 63;
                int i_loc = slot >> 3, j_loc = slot & 7;
                int bi = 0, remb = b;
                while (remb >= 8 - bi) { remb -= 8 - bi; bi++; }
                int bj = bi + remb;
                int i = bi * 8 + i_loc, j = bj * 8 + j_loc;
                w = ldf(cpst_w, (size_t)n * 4096 + i * 64 + j, isb);
                if (bi != bj)
                    w += ldf(cpst_w, (size_t)n * 4096 + j * 64 + i, isb);
            } else {
                w = ldf(cps_w, (size_t)n * 128 + (k - 2304), isb);
            }
            g_cpstU[d] = f2h(w);
        }
        // ---- g_cprtU: plain layout (33 stages) ----
        for (int d = gid; d < 64 * W2F; d += stride) {
            int s    = d / STG;
            int rem  = d - s * STG;
            int kbl  = rem >> 11;
            int rem2 = rem & 2047;
            int nt   = rem2 >> 9;
            int rem3 = rem2 & 511;
            int q    = rem3 >> 7;
            int rem4 = rem3 & 127;
            int sub  = rem4 >> 3;
            int z    = rem4 & 7;
            int n    = nt * 16 + sub;
            int k    = s * 128 + kbl * 32 + q * 8 + z;
            float v2 = (k < 4096) ? ldf(cprt_w, (size_t)n * 4096 + k, isb)
                                  : ldf(cpr_w,  (size_t)n * 128 + (k - 4096), isb);
            g_cprtU[d] = f2h(v2);
        }
        for (int i = gid; i < 448; i += stride) g_smw[i] = ldf(sm_w, i, isb);
        if (gid < 64) {
            g_biasC[gid] = ldf(cps_b, gid, isb) + ldf(cpst_b, gid, isb);
            g_biasF[gid] = ldf(cpr_b, gid, isb) + ldf(cprt_b, gid, isb);
        }
        if (gid < 7) g_smb[gid] = ldf(sm_b, gid, isb);
    } else {
        int t = threadIdx.x;
        if (t < 64) vb[t] = ldf(voc_b, t, isb);
        int v0 = (blockIdx.x - 512) * 64;
        int vl = t & 63, dr = t >> 6;
        #pragma unroll
        for (int i = 0; i < 16; i++) {
            int d = dr * 16 + i;
            int v = v0 + vl;
            tile[vl][d] = (v < VOC) ? ldf(voc_w, (size_t)d * VOC + v, isb) : 0.f;
        }
        __syncthreads();
        int dl = t & 63, vr0 = t >> 6;
        #pragma unroll
        for (int i = 0; i < 16; i++) {
            int vr = vr0 * 16 + i;
            int v = v0 + vr;
            if (v < VOC) g_vocT[(size_t)v * 64 + dl] = f2h(tile[vr][dl] + vb[dl]);
        }
    }
}

// epilogue for owned chunk CO (literal index!): add bias, tanh, store (f16)
#define EPILOGUE(CO)                                                          \
    if (lv < 5) {                                                             \
        _Pragma("unroll")                                                     \
        for (int nt = 0; nt < 4; nt++) {                                      \
            int e = nt * 16 + sub;                                            \
            _Pragma("unroll")                                                 \
            for (int rr = 0; rr < 4; rr++) {                                  \
                int m = chv[CO] * 16 + q * 4 + rr;                            \
                if (m < nodes) {                                              \
                    int t2 = m >> lg, n2 = m & (cnew - 1);                    \
                    Xs[(t2 * 64 + n2) * XSTR + e] =                           \
                        f2h(tanhf(scrub(acc[CO][nt][rr] + biasC[e])));        \
                }                                                             \
            }                                                                 \
        }                                                                     \
    } else {                                                                  \
        _Pragma("unroll")                                                     \
        for (int nt = 0; nt < 4; nt++) {                                      \
            int e = nt * 16 + sub;                                            \
            _Pragma("unroll")                                                 \
            for (int rr = 0; rr < 4; rr++) {                                  \
                int m = q * 4 + rr;                                           \
                if (m < TPW)                                                  \
                    g_roots[((size_t)wg * TPW + m) * 64 + e] =                \
                        f2h(tanhf(scrub(acc[CO][nt][rr] + biasC[e])));        \
            }                                                                 \
        }                                                                     \
    }

// send partial acc for chunk CS (literal) to this wave's scratch slot
#define EXSEND(CS)                                                            \
    { _Pragma("unroll")                                                       \
      for (int nt = 0; nt < 4; nt++)                                          \
          *(f32x4*)(exchS + wave * 1024 + nt * 256 + lane * 4) = acc[CS][nt]; }

// receive partner's partial for owned chunk CO (literal) and accumulate
#define EXRECV(CO)                                                            \
    { _Pragma("unroll")                                                       \
      for (int nt = 0; nt < 4; nt++) {                                        \
          f32x4 v_ = *(const f32x4*)(exchS + (wave ^ 1) * 1024 + nt * 256 + lane * 4); \
          _Pragma("unroll")                                                   \
      for (int z = 0; z < 4; z++) acc[CO][nt][z] += v_[z];                    \
      } }

// ---------- kernel: full tree composition (symmetric-folded K) ----------
// 512 thr = 8 waves = 4 pairs, 1 WG/CU.  Pair p = wave>>1 owns M-chunks
// ch = p + 4c; wave half = wave&1 takes kron block b = 2s+half of stage s
// (or the L/R half of the concat stage).  Block b -> (bi,bj): afr[z] =
// L[bi*8+p2*4+q] * L[bj*8+z] (one f16x8 read + scalar per p2 -> pk_mul).
// Weights via global_load_lds, double-buffered, ONE barrier per stage.
// K-partials exchanged via dedicated exchS once per level.
__global__ __launch_bounds__(512, 2) void k_tree(const int* __restrict__ lleaf,
                                                 const int* __restrict__ rleaf)
{
    __shared__ __attribute__((aligned(16))) unsigned short Xs[512 * XSTR];  // 73728 B
    __shared__ __attribute__((aligned(16))) unsigned short Bs[2][STG];      // 32768 B
    __shared__ __attribute__((aligned(16))) float exchS[8192];              // 32768 B
    __shared__ float biasC[64];
    const int tid = threadIdx.x;
    const int wg  = blockIdx.x;

    // ---- issue weight stage 0 into Bs[0] (overlaps leaf gather) ----
    gload16(g_cpstU + tid * 8, Bs[0] + tid * 8);
    gload16(g_cpstU + 4096 + tid * 8, Bs[0] + 4096 + tid * 8);

    if (tid < 64) biasC[tid] = g_biasC[tid];

    // ---- leaf gather: row tid = (tree tid>>6, leaf tid&63) ----
    {
        int t = tid >> 6, i = tid & 63;
        int gidx = wg * TPW + t;                 // 0..1023 left, 1024..2047 right
        int b = (gidx < 1024) ? gidx : gidx - 1024;
        const int* lv2 = (gidx < 1024) ? lleaf : rleaf;
        int idx = lv2[b * 64 + i];
        idx = (idx < 0) ? 0 : ((idx >= VOC) ? VOC - 1 : idx);
        const uint4* src = (const uint4*)(g_vocT + (size_t)idx * 64);
        uint4* dst = (uint4*)(Xs + tid * XSTR);
        #pragma unroll
        for (int z = 0; z < 8; z++) dst[z] = src[z];
    }

    __syncthreads();   // Xs + biasC ready; stage-0 DMA drained (own vmcnt)

    const int lane = tid & 63, wave = tid >> 6;
    const int q = lane >> 4, sub = lane & 15;
    const int p = wave >> 1, half = wave & 1;
    int par = 0;

    for (int lv = 0; lv < 6; lv++) {
        const int lg = 5 - lv;
        const int cnew = 1 << lg;
        const int nodes = TPW << lg;             // 256,128,64,32,16,8
        const int nchunks = (nodes + 15) >> 4;   // 16,8,4,2,1,1

        // ---- hoist: chunk geometry (registers, literal idx) ----
        int act[4], chv[4], slotL[4];
        #pragma unroll
        for (int c = 0; c < 4; c++) {
            int ch = p + 4 * c;
            act[c] = (ch < nchunks);
            chv[c] = ch;
            int m = ch * 16 + sub;
            if (!act[c] || m >= nodes) m = 0;
            int t = m >> lg, n = m & (cnew - 1);
            slotL[c] = (t * 64 + 2 * n) * XSTR;
        }

        f32x4 acc[4][4];                         // [chunk][ntile] K-partials
        #pragma unroll
        for (int c = 0; c < 4; c++)
            #pragma unroll
            for (int nt = 0; nt < 4; nt++)
                #pragma unroll
                for (int z = 0; z < 4; z++) acc[c][nt][z] = 0.f;

        for (int s = 0; s < NSTG_T; s++) {
            // issue next stage into the other buffer (wraps to 0: same weights)
            if (!(lv == 5 && s == NSTG_T - 1)) {
                int sn = (s == NSTG_T - 1) ? 0 : s + 1;
                const unsigned short* src = g_cpstU + (size_t)sn * STG;
                unsigned short* dst = Bs[par ^ 1];
                gload16(src + tid * 8, dst + tid * 8);
                gload16(src + 4096 + tid * 8, dst + 4096 + tid * 8);
            }
            const unsigned short* Bp = Bs[par];
            if (act[0]) {                        // act monotone in c: act[0] == any
                if (s < NSTG_T - 1) {            // kron: this wave does block 2s+half
                    int b = 2 * s + half;
                    int bi = 0, remb = b;
                    while (remb >= 8 - bi) { remb -= 8 - bi; bi++; }
                    int bj = bi + remb;
                    const int ofsV = bj * 8;
                    const int ofs0 = bi * 8 + q;
                    const int ofs1 = bi * 8 + 4 + q;
                    f16x8 Lb[4]; _Float16 l0[4], l1[4];
                    #pragma unroll
                    for (int c = 0; c < 4; c++) {
                        Lb[c] = *(const f16x8*)(Xs + slotL[c] + ofsV);
                        l0[c] = __builtin_bit_cast(_Float16, Xs[slotL[c] + ofs0]);
                        l1[c] = __builtin_bit_cast(_Float16, Xs[slotL[c] + ofs1]);
                    }
                    #pragma unroll
                    for (int p2 = 0; p2 < 2; p2++) {
                        const unsigned short* bb = Bp + (2 * half + p2) * 2048 + lane * 8;
                        f16x8 b0 = *(const f16x8*)(bb);
                        f16x8 b1 = *(const f16x8*)(bb + 512);
                        f16x8 b2 = *(const f16x8*)(bb + 1024);
                        f16x8 b3 = *(const f16x8*)(bb + 1536);
                        #pragma unroll
                        for (int c = 0; c < 4; c++) {
                            if (!act[c]) continue;
                            f16x8 afr = Lb[c] * (p2 ? l1[c] : l0[c]);   // pk_mul x4
                            acc[c][0] = __builtin_amdgcn_mfma_f32_16x16x32_f16(afr, b0, acc[c][0], 0, 0, 0);
                            acc[c][1] = __builtin_amdgcn_mfma_f32_16x16x32_f16(afr, b1, acc[c][1], 0, 0, 0);
                            acc[c][2] = __builtin_amdgcn_mfma_f32_16x16x32_f16(afr, b2, acc[c][2], 0, 0, 0);
                            acc[c][3] = __builtin_amdgcn_mfma_f32_16x16x32_f16(afr, b3, acc[c][3], 0, 0, 0);
                        }
                    }
                } else {                         // concat: half=0 -> L, half=1 -> R
                    #pragma unroll
                    for (int p2 = 0; p2 < 2; p2++) {
                        const unsigned short* bb = Bp + (2 * half + p2) * 2048 + lane * 8;
                        f16x8 b0 = *(const f16x8*)(bb);
                        f16x8 b1 = *(const f16x8*)(bb + 512);
                        f16x8 b2 = *(const f16x8*)(bb + 1024);
                        f16x8 b3 = *(const f16x8*)(bb + 1536);
                        #pragma unroll
                        for (int c = 0; c < 4; c++) {
                            if (!act[c]) continue;
                            f16x8 A = *(const f16x8*)(Xs + slotL[c] + half * XSTR + p2 * 32 + q * 8);
                            acc[c][0] = __builtin_amdgcn_mfma_f32_16x16x32_f16(A, b0, acc[c][0], 0, 0, 0);
                            acc[c][1] = __builtin_amdgcn_mfma_f32_16x16x32_f16(A, b1, acc[c][1], 0, 0, 0);
                            acc[c][2] = __builtin_amdgcn_mfma_f32_16x16x32_f16(A, b2, acc[c][2], 0, 0, 0);
                            acc[c][3] = __builtin_amdgcn_mfma_f32_16x16x32_f16(A, b3, acc[c][3], 0, 0, 0);
                        }
                    }
                }
            }
            __syncthreads();   // own DMA drained; all reads of Bs[par] done
            par ^= 1;
        }

        // ---- pair exchange + epilogue (exchS disjoint from Bs: the next
        // level's stage-0 DMA already in flight into Bs is safe) ----
        // round 0: chunks {0,1}; owned(c) iff (c&1)==half
        if (half == 0) { if (act[1]) EXSEND(1) } else { if (act[0]) EXSEND(0) }
        __syncthreads();
        if (half == 0) {
            if (act[0]) { EXRECV(0) EPILOGUE(0) }
        } else {
            if (act[1]) { EXRECV(1) EPILOGUE(1) }
        }
        __syncthreads();
        // round 1: chunks {2,3}
        if (half == 0) { if (act[3]) EXSEND(3) } else { if (act[2]) EXSEND(2) }
        __syncthreads();
        if (half == 0) {
            if (act[2]) { EXRECV(2) EPILOGUE(2) }
        } else {
            if (act[3]) { EXRECV(3) EPILOGUE(3) }
        }
        __syncthreads();   // Xs stable for next level's hoist
    }
}

// ---------- kernel: final cpr/cprt + leaky_relu + softmax ----------
// 64 WGs x 16 items, 4 waves; wave w owns N-tile nt = w (cols w*16..w*16+15).
// Asymmetric kron (l x r): plain 33-stage weight stream, gload_lds staging.
__global__ __launch_bounds__(256, 2) void k_final(const void* __restrict__ voc_b,
                                                  void* __restrict__ out)
{
    __shared__ __attribute__((aligned(16))) unsigned short Lv[IPW * XSTR], Rv[IPW * XSTR];
    __shared__ __attribute__((aligned(16))) unsigned short Bs[2][STG];
    __shared__ float actS[IPW][65];
    __shared__ float smw[7][64];
    __shared__ float smbS[7];
    __shared__ float biasF[64];
    const int tid = threadIdx.x, wg = blockIdx.x;
    const int isb = detect_isb(voc_b);

    // issue weight stage 0 into Bs[0]
    #pragma unroll
    for (int j = 0; j < 4; j++)
        gload16(g_cprtU + j * 2048 + tid * 8, Bs[0] + j * 2048 + tid * 8);

    if (tid < 64) biasF[tid] = g_biasF[tid];
    if (tid < 7)  smbS[tid] = g_smb[tid];
    for (int z = tid; z < 448; z += 256) smw[z >> 6][z & 63] = g_smw[z];

    {   // stage l and r roots for this WG's 16 items: 256 threads x 1 uint4
        int side = tid >> 7, idx = tid & 127;
        int item = idx >> 3, piece = idx & 7;
        const uint4* s4 = (const uint4*)(g_roots +
            ((size_t)(side * 1024) + (size_t)wg * IPW + item) * 64 + piece * 8);
        uint4* d4 = (uint4*)((side ? Rv : Lv) + item * XSTR + piece * 8);
        *d4 = *s4;
    }

    __syncthreads();   // roots + smem ready; stage-0 DMA drained

    const int lane = tid & 63, w = tid >> 6;
    const int q = lane >> 4, sub = lane & 15;
    const int rowLo = sub * XSTR;                // item = sub (A-operand rows)

    f16x8 Ra[2];                                 // kron = l[i] * r[j]
    Ra[0] = *(const f16x8*)(Rv + rowLo + q * 8);
    Ra[1] = *(const f16x8*)(Rv + rowLo + 32 + q * 8);

    f32x4 acc;
    #pragma unroll
    for (int z = 0; z < 4; z++) acc[z] = 0.f;

    int par = 0;
    for (int s = 0; s < NSTG_F; s++) {
        if (s < NSTG_F - 1) {
            const unsigned short* src = g_cprtU + (size_t)(s + 1) * STG;
            unsigned short* dst = Bs[par ^ 1];
            #pragma unroll
            for (int j = 0; j < 4; j++)
                gload16(src + j * 2048 + tid * 8, dst + j * 2048 + tid * 8);
        }
        const unsigned short* Bp = Bs[par];
        if (s < 32) {
            #pragma unroll
            for (int ii = 0; ii < 2; ii++) {
                int i = 2 * s + ii;
                _Float16 li = __builtin_bit_cast(_Float16, Lv[rowLo + i]);
                #pragma unroll
                for (int p2 = 0; p2 < 2; p2++) {
                    int kbl = 2 * ii + p2;
                    f16x8 bfr = *(const f16x8*)(Bp + kbl * 2048 + w * 512 + lane * 8);
                    f16x8 afr = Ra[p2] * li;
                    acc = __builtin_amdgcn_mfma_f32_16x16x32_f16(afr, bfr, acc, 0, 0, 0);
                }
            }
        } else {                                 // concat(l, r)
            f16x8 A4[4];
            A4[0] = *(const f16x8*)(Lv + rowLo + q * 8);
            A4[1] = *(const f16x8*)(Lv + rowLo + 32 + q * 8);
            A4[2] = *(const f16x8*)(Rv + rowLo + q * 8);
            A4[3] = *(const f16x8*)(Rv + rowLo + 32 + q * 8);
            #pragma unroll
            for (int kbl = 0; kbl < 4; kbl++) {
                f16x8 bfr = *(const f16x8*)(Bp + kbl * 2048 + w * 512 + lane * 8);
                acc = __builtin_amdgcn_mfma_f32_16x16x32_f16(A4[kbl], bfr, acc, 0, 0, 0);
            }
        }
        __syncthreads();
        par ^= 1;
    }

    // epilogue: bias + leaky_relu -> LDS  (actS disjoint from stage-loop LDS)
    {
        int e = w * 16 + sub;
        #pragma unroll
        for (int rr = 0; rr < 4; rr++) {
            int item = q * 4 + rr;
            float v = scrub(acc[rr] + biasF[e]);
            v = (v > 0.f) ? v : 0.01f * v;
            actS[item][e] = v;
        }
    }
    __syncthreads();

    if (tid < IPW) {
        float lg[7];
        #pragma unroll
        for (int j = 0; j < 7; j++) lg[j] = smbS[j];
        for (int e = 0; e < 64; e++) {
            float a = actS[tid][e];
            #pragma unroll
            for (int j = 0; j < 7; j++) lg[j] += smw[j][e] * a;
        }
        float mx = lg[0];
        #pragma unroll
        for (int j = 1; j < 7; j++) mx = fmaxf(mx, lg[j]);
        float s = 0.f, pr[7];
        #pragma unroll
        for (int j = 0; j < 7; j++) { pr[j] = expf(lg[j] - mx); s += pr[j]; }
        float inv = 1.f / s;
        size_t b = (size_t)wg * IPW + tid;
        if (isb) {
            unsigned short* o = (unsigned short*)out;
            #pragma unroll
            for (int j = 0; j < 7; j++) o[b * 7 + j] = f2b(pr[j] * inv);
        } else {
            float* o = (float*)out;
            #pragma unroll
            for (int j = 0; j < 7; j++) o[b * 7 + j] = pr[j] * inv;
        }
    }
}

// ---------- host launcher ----------
extern "C" void kernel_launch(void* const* d_in, const int* in_sizes, int n_in,
                              void* d_out, int out_size, void* d_ws, size_t ws_size,
                              hipStream_t stream) {
    const int* lleaf = (const int*)d_in[0];
    const int* rleaf = (const int*)d_in[1];
    const void* voc_w  = d_in[2];
    const void* voc_b  = d_in[3];
    const void* cps_w  = d_in[4];
    const void* cps_b  = d_in[5];
    const void* cpst_w = d_in[6];
    const void* cpst_b = d_in[7];
    const void* cpr_w  = d_in[8];
    const void* cpr_b  = d_in[9];
    const void* cprt_w = d_in[10];
    const void* cprt_b = d_in[11];
    const void* sm_w   = d_in[12];
    const void* sm_b   = d_in[13];

    k_prep<<<512 + (VOC + 63) / 64, 256, 0, stream>>>(
        voc_w, voc_b, cps_w, cps_b, cpst_w, cpst_b,
        cpr_w, cpr_b, cprt_w, cprt_b, sm_w, sm_b);
    k_tree<<<2048 / TPW, 512, 0, stream>>>(lleaf, rleaf);
    k_final<<<64, 256, 0, stream>>>(voc_b, (unsigned short*)d_out);
}